// Round 16
// baseline (420.027 us; speedup 1.0000x reference)
//
#include <hip/hip_runtime.h>
#include <math.h>

#define BB 64
#define PP 80
#define LC 18
#define EE 256
#define HH 1024
#define LCH 4
#define KW 3
#define TAGS 50
#define DD 260          // EE + LCH
#define KPAD 288        // DD padded to multiple of 32
#define ROWS (BB*PP)    // 5120
#define WN (LC-KW+1)    // 16
#define NG (4*HH)       // 4096 gate rows
#define GRP 4           // batch groups (16 batches each)
#define UPB 32          // units per block
#define NBLK (GRP*(HH/UPB))   // 128 persistent blocks
#define HSTEP32 (GRP*32*512)  // dwords per timestep: [4 g][32 kk][64 lane][8 e]

typedef __attribute__((ext_vector_type(8))) short short8;   // 8 x bf16
typedef __attribute__((ext_vector_type(4))) short short4v;  // 4 x bf16 (8B store)
typedef __attribute__((ext_vector_type(4))) float floatx4;  // MFMA acc
typedef __attribute__((ext_vector_type(4))) int int4v;      // 16B asm payload

__device__ __forceinline__ short f2bf(float x) {
    unsigned u = __float_as_uint(x);
    unsigned r = (u + 0x7FFFu + ((u >> 16) & 1u)) >> 16;
    return (short)r;
}
__device__ __forceinline__ float bf2f(short s) {
    return __uint_as_float(((unsigned)(unsigned short)s) << 16);
}
__device__ __forceinline__ float sigf(float x) { return 1.f / (1.f + __expf(-x)); }
__device__ __forceinline__ float tanhfast(float x) {
    float e = __expf(2.f * x);
    return 1.f - 2.f / (e + 1.f);
}
__device__ __forceinline__ float wave_reduce_sum(float v) {
    for (int off = 32; off > 0; off >>= 1) v += __shfl_xor(v, off, 64);
    return v;
}
// barrier that publishes LDS but leaves vmcnt (global loads/stores) in flight
__device__ __forceinline__ void lds_barrier() {
    asm volatile("s_waitcnt lgkmcnt(0)" ::: "memory");
    __builtin_amdgcn_sched_barrier(0);
    __builtin_amdgcn_s_barrier();
}

// ---- prep: wih pad->bf16, whh U=32 pack, outw pad, hst32 seq-clear ----------
__global__ __launch_bounds__(256) void prep_kernel(
    const float* __restrict__ wih, const float* __restrict__ whh,
    const float* __restrict__ outw,
    short* __restrict__ wih_bf, short* __restrict__ wpk,
    short* __restrict__ outw_bf, unsigned* __restrict__ hst32)
{
    const int NI = NG * KPAD;       // 1179648
    const int NH = NG * HH;         // 4194304
    const int NO = 64 * HH;         // 65536
    const int total = NI + NH + NO;
    for (int i = blockIdx.x * 256 + threadIdx.x; i < total; i += gridDim.x * 256) {
        if (i < NI) {
            int r = i / KPAD, c = i - r * KPAD;
            wih_bf[i] = (c < DD) ? f2bf(wih[r * DD + c]) : (short)0;
        } else if (i < NI + NH) {
            int o = i - NI;
            // wpk[bl32][w8][tl8][s4][lane64][e8]
            //   <- whh[(tl>>1)*HH + bl*32 + (tl&1)*16 + (l&15)]
            //         [w*128 + s*32 + (l>>4)*8 + e]
            int e  = o & 7;
            int l  = (o >> 3) & 63;
            int s  = (o >> 9) & 3;
            int tl = (o >> 11) & 7;
            int w  = (o >> 14) & 7;
            int bl = o >> 17;
            int row = (tl >> 1) * HH + bl * 32 + (tl & 1) * 16 + (l & 15);
            int col = w * 128 + s * 32 + (l >> 4) * 8 + e;
            wpk[o] = f2bf(whh[(size_t)row * HH + col]);
        } else {
            int k = i - NI - NH;
            int r = k >> 10;
            outw_bf[k] = (r < TAGS) ? f2bf(outw[k]) : (short)0;
        }
    }
    // clear h exchange buffer each launch: seq field 0 never matches t in [1,79]
    int4v z = {0, 0, 0, 0};
    int4v* hz = (int4v*)hst32;
    const int NZ = PP * HSTEP32 / 4;
    for (int i = blockIdx.x * 256 + threadIdx.x; i < NZ; i += gridDim.x * 256)
        hz[i] = z;
}

// ---------------- embedding + char CNN -> X bf16 [5120][288] ----------------
__global__ __launch_bounds__(256) void embed_kernel(
    const int* __restrict__ sent, const int* __restrict__ chars,
    const float* __restrict__ word_emb, const float* __restrict__ char_emb,
    const float* __restrict__ conv_w, const float* __restrict__ conv_b,
    short* __restrict__ X)
{
    __shared__ float4 ce[LC * 64];
    __shared__ float phi[WN * LCH];
    __shared__ float charrep[LCH];
    const int r = blockIdx.x;
    const int t = threadIdx.x;
    const int lane = t & 63, wv = t >> 6;

    const int cbase = r * LC;
    for (int i = 0; i < 5; ++i) {
        int idx = i * 256 + t;
        if (idx < LC * 64) {
            int j = idx >> 6, e4 = idx & 63;
            int ch = chars[cbase + j];
            ce[idx] = ((const float4*)(char_emb + (size_t)ch * EE))[e4];
        }
    }
    float4 cw[KW][LCH];
    #pragma unroll
    for (int k = 0; k < KW; ++k)
        #pragma unroll
        for (int c = 0; c < LCH; ++c)
            cw[k][c] = ((const float4*)(conv_w + c * (KW * EE) + k * EE))[lane];
    __syncthreads();

    #pragma unroll
    for (int wi = 0; wi < 4; ++wi) {
        int w = wv + wi * 4;
        float acc[LCH] = {0.f, 0.f, 0.f, 0.f};
        #pragma unroll
        for (int k = 0; k < KW; ++k) {
            float4 v = ce[(w + k) * 64 + lane];
            #pragma unroll
            for (int c = 0; c < LCH; ++c)
                acc[c] += v.x * cw[k][c].x + v.y * cw[k][c].y +
                          v.z * cw[k][c].z + v.w * cw[k][c].w;
        }
        #pragma unroll
        for (int c = 0; c < LCH; ++c) {
            float s = wave_reduce_sum(acc[c]);
            if (lane == 0) phi[w * LCH + c] = s;
        }
    }
    __syncthreads();
    if (t < LCH) {
        float m = -1e30f;
        for (int w = 0; w < WN; ++w) m = fmaxf(m, phi[w * LCH + t]);
        charrep[t] = m + conv_b[t];
    }
    __syncthreads();

    const int word = sent[r];
    X[(size_t)r * KPAD + t] = f2bf(word_emb[(size_t)word * EE + t]);
    if (t < LCH) X[(size_t)r * KPAD + EE + t] = f2bf(charrep[t]);
    if (t >= 228) X[(size_t)r * KPAD + 32 + t] = (short)0;
}

// ---- input GEMM -> ginP[t][g][bl64][gate][uu16][b16] ------------------------
// LDS-transposed epilogue: MFMA tile -> sm[col][b] bf16 (+bias), then fully
// coalesced 32B stores matching the lstm consumer layout exactly.
__global__ __launch_bounds__(256) void gemm_in_kernel(
    const short* __restrict__ X, const short* __restrict__ Wih,
    const float* __restrict__ b_ih, const float* __restrict__ b_hh,
    short* __restrict__ ginP)
{
    __shared__ short sm[128][72];   // [colL][b], rows padded to 144B (16B-aligned)
    const int tid = threadIdx.x;
    const int l = tid & 63, wv = tid >> 6;
    const int t = blockIdx.x;                   // timestep (rows t*64 .. +63)
    const int n0 = blockIdx.y * 128 + wv * 32;  // global gate-col base of wave
    const int r0 = t * 64;
    const int lr = l & 15, lh = l >> 4;

    const float bias0 = b_ih[n0 + lr] + b_hh[n0 + lr];
    const float bias1 = b_ih[n0 + 16 + lr] + b_hh[n0 + 16 + lr];

    floatx4 acc[4][2];
    #pragma unroll
    for (int m = 0; m < 4; ++m)
        #pragma unroll
        for (int n = 0; n < 2; ++n) acc[m][n] = (floatx4)0.f;

    const short* Xb = X + (size_t)(r0 + lr) * KPAD + lh * 8;
    const short* Wb = Wih + (size_t)(n0 + lr) * KPAD + lh * 8;

    #pragma unroll
    for (int k0 = 0; k0 < KPAD; k0 += 32) {
        short8 a0 = *(const short8*)(Xb + k0);
        short8 a1 = *(const short8*)(Xb + 16 * KPAD + k0);
        short8 a2 = *(const short8*)(Xb + 32 * KPAD + k0);
        short8 a3 = *(const short8*)(Xb + 48 * KPAD + k0);
        short8 b0 = *(const short8*)(Wb + k0);
        short8 b1 = *(const short8*)(Wb + 16 * KPAD + k0);
        acc[0][0] = __builtin_amdgcn_mfma_f32_16x16x32_bf16(a0, b0, acc[0][0], 0, 0, 0);
        acc[1][0] = __builtin_amdgcn_mfma_f32_16x16x32_bf16(a1, b0, acc[1][0], 0, 0, 0);
        acc[2][0] = __builtin_amdgcn_mfma_f32_16x16x32_bf16(a2, b0, acc[2][0], 0, 0, 0);
        acc[3][0] = __builtin_amdgcn_mfma_f32_16x16x32_bf16(a3, b0, acc[3][0], 0, 0, 0);
        acc[0][1] = __builtin_amdgcn_mfma_f32_16x16x32_bf16(a0, b1, acc[0][1], 0, 0, 0);
        acc[1][1] = __builtin_amdgcn_mfma_f32_16x16x32_bf16(a1, b1, acc[1][1], 0, 0, 0);
        acc[2][1] = __builtin_amdgcn_mfma_f32_16x16x32_bf16(a2, b1, acc[2][1], 0, 0, 0);
        acc[3][1] = __builtin_amdgcn_mfma_f32_16x16x32_bf16(a3, b1, acc[3][1], 0, 0, 0);
    }
    // C fragment -> LDS transpose: row (batch b) = m*16+lh*4+q, col = n*16+lr
    #pragma unroll
    for (int m = 0; m < 4; ++m)
        #pragma unroll
        for (int n = 0; n < 2; ++n) {
            int colL = wv * 32 + n * 16 + lr;
            float bias = n ? bias1 : bias0;
            #pragma unroll
            for (int q = 0; q < 4; ++q)
                sm[colL][m * 16 + lh * 4 + q] = f2bf(acc[m][n][q] + bias);
        }
    __syncthreads();

    // coalesced store: 512 (colL, g) pairs x 32B contiguous each
    for (int j = tid; j < 512; j += 256) {
        int colL = j & 127, gg = j >> 7;
        int col = blockIdx.y * 128 + colL;
        int w_ = col >> 10, bl_ = (col >> 4) & 63, uu_ = col & 15;
        size_t base = ((((size_t)(t * GRP + gg) * 64 + bl_) * 4 + w_) * 16 + uu_) * 16;
        *(int4v*)(ginP + base)     = *(const int4v*)&sm[colL][gg * 16];
        *(int4v*)(ginP + base + 8) = *(const int4v*)&sm[colL][gg * 16 + 8];
    }
}

// ---------------- persistent LSTM: U=32, per-chunk retry, direct h store -----
// (identical to round-15 kernel: proven 273 us)
__global__ __launch_bounds__(512, 1) void lstm_seq_kernel(
    unsigned* __restrict__ hst, const short* __restrict__ wpk,
    const short* __restrict__ ginP)
{
    __shared__ __align__(16) float lds_g[8][8][16][20];

    const int tid = threadIdx.x;
    const int l = tid & 63;
    const int w = tid >> 6;             // wave 0..7 = K-chunk id
    const int g  = blockIdx.x >> 5;     // batch group (16 batches)
    const int bl = blockIdx.x & 31;     // unit block (32 units)

    short8 barr[8][4];
    {
        const short* wb = wpk + (size_t)(bl * 8 + w) * 16384 + l * 8;
        #pragma unroll
        for (int tl = 0; tl < 8; ++tl)
            #pragma unroll
            for (int s = 0; s < 4; ++s)
                barr[tl][s] = *(const short8*)(wb + tl * 2048 + s * 512);
    }

    const int b16 = tid & 15;
    const int uu  = tid >> 4;
    const int U_  = bl * 32 + uu;
    float c = 0.f;

    const size_t hoff = (size_t)g * 16384 + bl * 512
                        + ((uu >> 3) * 16 + b16) * 8 + (uu & 7);

    float gv[4];
    {
        const short* gb = ginP + (((size_t)g * 64 + (U_ >> 4)) * 4) * 256
                          + (U_ & 15) * 16 + b16;
        #pragma unroll
        for (int q = 0; q < 4; ++q) gv[q] = bf2f(gb[q * 256]);
    }

    for (int t = 0; t < PP; ++t) {
        if (t > 0) {
            const unsigned* A = hst + (size_t)(t - 1) * HSTEP32 + g * 16384
                                + (w * 4) * 512 + l * 8;
            int4v d[8];
            unsigned stale = 0xFu;
            do {
                #pragma unroll
                for (int s = 0; s < 4; ++s)
                    if (stale & (1u << s)) {
                        asm volatile("global_load_dwordx4 %0, %1, off sc0 sc1"
                                     : "=v"(d[2 * s]) : "v"(A + s * 512) : "memory");
                        asm volatile("global_load_dwordx4 %0, %1, off sc0 sc1"
                                     : "=v"(d[2 * s + 1]) : "v"(A + s * 512 + 4) : "memory");
                    }
                asm volatile("s_waitcnt vmcnt(0)" ::: "memory");
                __builtin_amdgcn_sched_barrier(0);
                #pragma unroll
                for (int s = 0; s < 4; ++s)
                    if (stale & (1u << s)) {
                        int ok = 1;
                        #pragma unroll
                        for (int i = 0; i < 2; ++i)
                            #pragma unroll
                            for (int j = 0; j < 4; ++j)
                                ok &= ((((unsigned)d[2 * s + i][j]) & 0xFFFFu)
                                       == (unsigned)t);
                        if (__all(ok)) stale &= ~(1u << s);
                    }
                if (stale) __builtin_amdgcn_s_sleep(1);
            } while (stale);

            floatx4 acc[8];
            #pragma unroll
            for (int tl = 0; tl < 8; ++tl) acc[tl] = (floatx4)0.f;
            #pragma unroll
            for (int s = 0; s < 4; ++s) {
                int4v pk;
                pk[0] = (int)((((unsigned)d[2*s][0]) >> 16)   | (((unsigned)d[2*s][1])   & 0xFFFF0000u));
                pk[1] = (int)((((unsigned)d[2*s][2]) >> 16)   | (((unsigned)d[2*s][3])   & 0xFFFF0000u));
                pk[2] = (int)((((unsigned)d[2*s+1][0]) >> 16) | (((unsigned)d[2*s+1][1]) & 0xFFFF0000u));
                pk[3] = (int)((((unsigned)d[2*s+1][2]) >> 16) | (((unsigned)d[2*s+1][3]) & 0xFFFF0000u));
                short8 av = __builtin_bit_cast(short8, pk);
                #pragma unroll
                for (int tl = 0; tl < 8; ++tl)
                    acc[tl] = __builtin_amdgcn_mfma_f32_16x16x32_bf16(
                        av, barr[tl][s], acc[tl], 0, 0, 0);
            }
            #pragma unroll
            for (int tl = 0; tl < 8; ++tl)
                *(floatx4*)&lds_g[w][tl][l & 15][(l >> 4) * 4] = acc[tl];
            lds_barrier();   // publish LDS; vmcnt (h-store ack) stays in flight
        }

        {
            float s0 = gv[0], s1 = gv[1], s2 = gv[2], s3 = gv[3];
            if (t > 0) {
                #pragma unroll
                for (int w2 = 0; w2 < 8; ++w2) {
                    s0 += lds_g[w2][0 + (uu >> 4)][uu & 15][b16];
                    s1 += lds_g[w2][2 + (uu >> 4)][uu & 15][b16];
                    s2 += lds_g[w2][4 + (uu >> 4)][uu & 15][b16];
                    s3 += lds_g[w2][6 + (uu >> 4)][uu & 15][b16];
                }
            }
            float i_ = sigf(s0), f_ = sigf(s1), g_ = tanhfast(s2), o_ = sigf(s3);
            c = f_ * c + i_ * g_;
            unsigned hd = (((unsigned)(unsigned short)f2bf(o_ * tanhfast(c))) << 16)
                          | (unsigned)(t + 1);
            unsigned* hp = hst + (size_t)t * HSTEP32 + hoff;
            asm volatile("global_store_dword %0, %1, off sc0 sc1"
                         :: "v"(hp), "v"(hd) : "memory");

            if (t + 1 < PP) {
                const short* gb = ginP + ((((size_t)(t + 1) * GRP + g) * 64
                                          + (U_ >> 4)) * 4) * 256 + (U_ & 15) * 16 + b16;
                #pragma unroll
                for (int q = 0; q < 4; ++q) gv[q] = bf2f(gb[q * 256]);
            }
        }
        lds_barrier();   // protect lds_g reuse next step; no vmcnt drain
    }
}

// -------- tag head + log_softmax fused: one block per batch b ---------------
__global__ __launch_bounds__(256) void tagsm_kernel(
    const unsigned* __restrict__ hst, const short* __restrict__ outw_bf,
    const float* __restrict__ out_b, float* __restrict__ out)
{
    __shared__ float sm[PP][52];
    __shared__ float lzb[64];
    const int tid = threadIdx.x;
    const int l = tid & 63, wv = tid >> 6;
    const int b = blockIdx.x;
    const int lr = l & 15, lh = l >> 4;

    const short* Bw = outw_bf + (size_t)(wv * 16 + lr) * HH + lh * 8;

    floatx4 acc[5];
    #pragma unroll
    for (int m = 0; m < 5; ++m) acc[m] = (floatx4)0.f;

    for (int kk = 0; kk < 32; ++kk) {
        short8 bfr = *(const short8*)(Bw + kk * 32);
        #pragma unroll
        for (int m = 0; m < 5; ++m) {
            int q = b * PP + m * 16 + lr;        // flat row (t,b2) = q
            int t = q >> 6, gg = (q >> 4) & 3, b16 = q & 15;
            const unsigned* ap = hst + (size_t)t * HSTEP32 + gg * 16384
                                 + kk * 512 + (lh * 16 + b16) * 8;
            int4v d0 = *(const int4v*)(ap);
            int4v d1 = *(const int4v*)(ap + 4);
            int4v pk;
            pk[0] = (int)((((unsigned)d0[0]) >> 16) | (((unsigned)d0[1]) & 0xFFFF0000u));
            pk[1] = (int)((((unsigned)d0[2]) >> 16) | (((unsigned)d0[3]) & 0xFFFF0000u));
            pk[2] = (int)((((unsigned)d1[0]) >> 16) | (((unsigned)d1[1]) & 0xFFFF0000u));
            pk[3] = (int)((((unsigned)d1[2]) >> 16) | (((unsigned)d1[3]) & 0xFFFF0000u));
            short8 a = __builtin_bit_cast(short8, pk);
            acc[m] = __builtin_amdgcn_mfma_f32_16x16x32_bf16(a, bfr, acc[m], 0, 0, 0);
        }
    }
    int col = wv * 16 + lr;
    if (col < TAGS) {
        float bias = out_b[col];
        #pragma unroll
        for (int m = 0; m < 5; ++m)
            #pragma unroll
            for (int q4 = 0; q4 < 4; ++q4)
                sm[m * 16 + lh * 4 + q4][col] = acc[m][q4] + bias;
    }
    __syncthreads();

    if (tid < TAGS) {
        float mx = -1e30f;
        for (int p = 0; p < PP; ++p) mx = fmaxf(mx, sm[p][tid]);
        float s = 0.f;
        for (int p = 0; p < PP; ++p) s += __expf(sm[p][tid] - mx);
        lzb[tid] = mx + __logf(s);
    }
    __syncthreads();

    for (int idx = tid; idx < PP * TAGS; idx += 256) {
        int p = idx / TAGS, j = idx - p * TAGS;
        out[(size_t)b * (PP * TAGS) + idx] = sm[p][j] - lzb[j];
    }
}

extern "C" void kernel_launch(void* const* d_in, const int* in_sizes, int n_in,
                              void* d_out, int out_size, void* d_ws, size_t ws_size,
                              hipStream_t stream)
{
    const int*   sent     = (const int*)d_in[0];
    const int*   chars    = (const int*)d_in[1];
    const float* word_emb = (const float*)d_in[2];
    const float* char_emb = (const float*)d_in[3];
    const float* conv_w   = (const float*)d_in[4];
    const float* conv_b   = (const float*)d_in[5];
    const float* w_ih     = (const float*)d_in[6];
    const float* w_hh     = (const float*)d_in[7];
    const float* b_ih     = (const float*)d_in[8];
    const float* b_hh     = (const float*)d_in[9];
    const float* out_w    = (const float*)d_in[10];
    const float* out_b    = (const float*)d_in[11];
    float* out = (float*)d_out;

    short* X_bf     = (short*)d_ws;                            // 5120*288
    short* wih_bf   = X_bf + (size_t)ROWS * KPAD;              // 4096*288
    short* wpk      = wih_bf + (size_t)NG * KPAD;              // 4096*1024 (frag-major)
    short* outw_bf  = wpk + (size_t)NG * HH;                   // 64*1024
    short* ginP     = outw_bf + (size_t)64 * HH;               // 4096*5120
    unsigned* hst32 = (unsigned*)(ginP + (size_t)NG * ROWS);   // 80*HSTEP32 dwords

    hipLaunchKernelGGL(prep_kernel, dim3(2048), dim3(256), 0, stream,
                       w_ih, w_hh, out_w, wih_bf, wpk, outw_bf, hst32);
    hipLaunchKernelGGL(embed_kernel, dim3(ROWS), dim3(256), 0, stream,
                       sent, chars, word_emb, char_emb, conv_w, conv_b, X_bf);
    hipLaunchKernelGGL(gemm_in_kernel, dim3(PP, NG / 128), dim3(256), 0, stream,
                       X_bf, wih_bf, b_ih, b_hh, ginP);
    {
        void* kargs[3] = { (void*)&hst32, (void*)&wpk, (void*)&ginP };
        hipLaunchCooperativeKernel((void*)lstm_seq_kernel, dim3(NBLK), dim3(512),
                                   kargs, 0, stream);
    }
    hipLaunchKernelGGL(tagsm_kernel, dim3(BB), dim3(256), 0, stream,
                       hst32, outw_bf, out_b, out);
}

// Round 17
// 395.166 us; speedup vs baseline: 1.0629x; 1.0629x over previous
//
#include <hip/hip_runtime.h>
#include <math.h>

#define BB 64
#define PP 80
#define LC 18
#define EE 256
#define HH 1024
#define LCH 4
#define KW 3
#define TAGS 50
#define DD 260          // EE + LCH
#define KPAD 288        // DD padded to multiple of 32
#define ROWS (BB*PP)    // 5120
#define WN (LC-KW+1)    // 16
#define NG (4*HH)       // 4096 gate rows
#define GRP 4           // batch groups (16 batches each)
#define UPB 32          // units per block
#define NBLK (GRP*(HH/UPB))   // 128 persistent blocks
#define HSTEP32 (GRP*32*512)  // dwords per timestep: [4 g][32 kk][64 lane][8 e]
#define PREPB 2048            // prep blocks inside fused prep_embed kernel

typedef __attribute__((ext_vector_type(8))) short short8;   // 8 x bf16
typedef __attribute__((ext_vector_type(4))) short short4v;  // 4 x bf16 (8B store)
typedef __attribute__((ext_vector_type(4))) float floatx4;  // MFMA acc
typedef __attribute__((ext_vector_type(4))) int int4v;      // 16B asm payload

__device__ __forceinline__ short f2bf(float x) {
    unsigned u = __float_as_uint(x);
    unsigned r = (u + 0x7FFFu + ((u >> 16) & 1u)) >> 16;
    return (short)r;
}
__device__ __forceinline__ float bf2f(short s) {
    return __uint_as_float(((unsigned)(unsigned short)s) << 16);
}
__device__ __forceinline__ float sigf(float x) { return 1.f / (1.f + __expf(-x)); }
__device__ __forceinline__ float tanhfast(float x) {
    float e = __expf(2.f * x);
    return 1.f - 2.f / (e + 1.f);
}
__device__ __forceinline__ float wave_reduce_sum(float v) {
    for (int off = 32; off > 0; off >>= 1) v += __shfl_xor(v, off, 64);
    return v;
}
// barrier that publishes LDS but leaves vmcnt (global loads/stores) in flight
__device__ __forceinline__ void lds_barrier() {
    asm volatile("s_waitcnt lgkmcnt(0)" ::: "memory");
    __builtin_amdgcn_sched_barrier(0);
    __builtin_amdgcn_s_barrier();
}

// ---- fused prep (blocks 0..2047) + embed (blocks 2048..7167) ----------------
// prep: wih pad->bf16, whh U=32 frag pack, outw pad, hst32 seq-clear.
// embed: char CNN + word emb -> X bf16 [5120][288].
__global__ __launch_bounds__(256) void prep_embed_kernel(
    const float* __restrict__ wih, const float* __restrict__ whh,
    const float* __restrict__ outw,
    short* __restrict__ wih_bf, short* __restrict__ wpk,
    short* __restrict__ outw_bf, unsigned* __restrict__ hst32,
    const int* __restrict__ sent, const int* __restrict__ chars,
    const float* __restrict__ word_emb, const float* __restrict__ char_emb,
    const float* __restrict__ conv_w, const float* __restrict__ conv_b,
    short* __restrict__ X)
{
    if (blockIdx.x < PREPB) {
        // ---------------- prep branch ----------------
        const int NI = NG * KPAD;       // 1179648
        const int NH = NG * HH;         // 4194304
        const int NO = 64 * HH;         // 65536
        const int total = NI + NH + NO;
        const int stride = PREPB * 256;
        for (int i = blockIdx.x * 256 + threadIdx.x; i < total; i += stride) {
            if (i < NI) {
                int r = i / KPAD, c = i - r * KPAD;
                wih_bf[i] = (c < DD) ? f2bf(wih[r * DD + c]) : (short)0;
            } else if (i < NI + NH) {
                int o = i - NI;
                // wpk[bl32][w8][tl8][s4][lane64][e8]
                int e  = o & 7;
                int l  = (o >> 3) & 63;
                int s  = (o >> 9) & 3;
                int tl = (o >> 11) & 7;
                int w  = (o >> 14) & 7;
                int bl = o >> 17;
                int row = (tl >> 1) * HH + bl * 32 + (tl & 1) * 16 + (l & 15);
                int col = w * 128 + s * 32 + (l >> 4) * 8 + e;
                wpk[o] = f2bf(whh[(size_t)row * HH + col]);
            } else {
                int k = i - NI - NH;
                int r = k >> 10;
                outw_bf[k] = (r < TAGS) ? f2bf(outw[k]) : (short)0;
            }
        }
        // clear h exchange buffer: seq field 0 never matches t in [1,79]
        int4v z = {0, 0, 0, 0};
        int4v* hz = (int4v*)hst32;
        const int NZ = PP * HSTEP32 / 4;
        for (int i = blockIdx.x * 256 + threadIdx.x; i < NZ; i += stride)
            hz[i] = z;
        return;
    }

    // ---------------- embed branch ----------------
    __shared__ float4 ce[LC * 64];
    __shared__ float phi[WN * LCH];
    __shared__ float charrep[LCH];
    const int r = blockIdx.x - PREPB;
    const int t = threadIdx.x;
    const int lane = t & 63, wv = t >> 6;

    const int cbase = r * LC;
    for (int i = 0; i < 5; ++i) {
        int idx = i * 256 + t;
        if (idx < LC * 64) {
            int j = idx >> 6, e4 = idx & 63;
            int ch = chars[cbase + j];
            ce[idx] = ((const float4*)(char_emb + (size_t)ch * EE))[e4];
        }
    }
    float4 cw[KW][LCH];
    #pragma unroll
    for (int k = 0; k < KW; ++k)
        #pragma unroll
        for (int c = 0; c < LCH; ++c)
            cw[k][c] = ((const float4*)(conv_w + c * (KW * EE) + k * EE))[lane];
    __syncthreads();

    #pragma unroll
    for (int wi = 0; wi < 4; ++wi) {
        int w = wv + wi * 4;
        float acc[LCH] = {0.f, 0.f, 0.f, 0.f};
        #pragma unroll
        for (int k = 0; k < KW; ++k) {
            float4 v = ce[(w + k) * 64 + lane];
            #pragma unroll
            for (int c = 0; c < LCH; ++c)
                acc[c] += v.x * cw[k][c].x + v.y * cw[k][c].y +
                          v.z * cw[k][c].z + v.w * cw[k][c].w;
        }
        #pragma unroll
        for (int c = 0; c < LCH; ++c) {
            float s = wave_reduce_sum(acc[c]);
            if (lane == 0) phi[w * LCH + c] = s;
        }
    }
    __syncthreads();
    if (t < LCH) {
        float m = -1e30f;
        for (int w = 0; w < WN; ++w) m = fmaxf(m, phi[w * LCH + t]);
        charrep[t] = m + conv_b[t];
    }
    __syncthreads();

    const int word = sent[r];
    X[(size_t)r * KPAD + t] = f2bf(word_emb[(size_t)word * EE + t]);
    if (t < LCH) X[(size_t)r * KPAD + EE + t] = f2bf(charrep[t]);
    if (t >= 228) X[(size_t)r * KPAD + 32 + t] = (short)0;
}

// ---- input GEMM -> ginP[t][g][bl64][gate][uu16][b16] ------------------------
// LDS-transposed epilogue -> fully coalesced 32B stores (r16, proven).
__global__ __launch_bounds__(256) void gemm_in_kernel(
    const short* __restrict__ X, const short* __restrict__ Wih,
    const float* __restrict__ b_ih, const float* __restrict__ b_hh,
    short* __restrict__ ginP)
{
    __shared__ short sm[128][72];   // [colL][b], rows padded (16B-aligned)
    const int tid = threadIdx.x;
    const int l = tid & 63, wv = tid >> 6;
    const int t = blockIdx.x;
    const int n0 = blockIdx.y * 128 + wv * 32;
    const int r0 = t * 64;
    const int lr = l & 15, lh = l >> 4;

    const float bias0 = b_ih[n0 + lr] + b_hh[n0 + lr];
    const float bias1 = b_ih[n0 + 16 + lr] + b_hh[n0 + 16 + lr];

    floatx4 acc[4][2];
    #pragma unroll
    for (int m = 0; m < 4; ++m)
        #pragma unroll
        for (int n = 0; n < 2; ++n) acc[m][n] = (floatx4)0.f;

    const short* Xb = X + (size_t)(r0 + lr) * KPAD + lh * 8;
    const short* Wb = Wih + (size_t)(n0 + lr) * KPAD + lh * 8;

    #pragma unroll
    for (int k0 = 0; k0 < KPAD; k0 += 32) {
        short8 a0 = *(const short8*)(Xb + k0);
        short8 a1 = *(const short8*)(Xb + 16 * KPAD + k0);
        short8 a2 = *(const short8*)(Xb + 32 * KPAD + k0);
        short8 a3 = *(const short8*)(Xb + 48 * KPAD + k0);
        short8 b0 = *(const short8*)(Wb + k0);
        short8 b1 = *(const short8*)(Wb + 16 * KPAD + k0);
        acc[0][0] = __builtin_amdgcn_mfma_f32_16x16x32_bf16(a0, b0, acc[0][0], 0, 0, 0);
        acc[1][0] = __builtin_amdgcn_mfma_f32_16x16x32_bf16(a1, b0, acc[1][0], 0, 0, 0);
        acc[2][0] = __builtin_amdgcn_mfma_f32_16x16x32_bf16(a2, b0, acc[2][0], 0, 0, 0);
        acc[3][0] = __builtin_amdgcn_mfma_f32_16x16x32_bf16(a3, b0, acc[3][0], 0, 0, 0);
        acc[0][1] = __builtin_amdgcn_mfma_f32_16x16x32_bf16(a0, b1, acc[0][1], 0, 0, 0);
        acc[1][1] = __builtin_amdgcn_mfma_f32_16x16x32_bf16(a1, b1, acc[1][1], 0, 0, 0);
        acc[2][1] = __builtin_amdgcn_mfma_f32_16x16x32_bf16(a2, b1, acc[2][1], 0, 0, 0);
        acc[3][1] = __builtin_amdgcn_mfma_f32_16x16x32_bf16(a3, b1, acc[3][1], 0, 0, 0);
    }
    #pragma unroll
    for (int m = 0; m < 4; ++m)
        #pragma unroll
        for (int n = 0; n < 2; ++n) {
            int colL = wv * 32 + n * 16 + lr;
            float bias = n ? bias1 : bias0;
            #pragma unroll
            for (int q = 0; q < 4; ++q)
                sm[colL][m * 16 + lh * 4 + q] = f2bf(acc[m][n][q] + bias);
        }
    __syncthreads();

    for (int j = tid; j < 512; j += 256) {
        int colL = j & 127, gg = j >> 7;
        int col = blockIdx.y * 128 + colL;
        int w_ = col >> 10, bl_ = (col >> 4) & 63, uu_ = col & 15;
        size_t base = ((((size_t)(t * GRP + gg) * 64 + bl_) * 4 + w_) * 16 + uu_) * 16;
        *(int4v*)(ginP + base)     = *(const int4v*)&sm[colL][gg * 16];
        *(int4v*)(ginP + base + 8) = *(const int4v*)&sm[colL][gg * 16 + 8];
    }
}

// ---------------- persistent LSTM: U=32, per-chunk retry, direct h store -----
// (identical recurrent core to rounds 11/15/16: proven 273 us; plain launch)
__global__ __launch_bounds__(512, 1) void lstm_seq_kernel(
    unsigned* __restrict__ hst, const short* __restrict__ wpk,
    const short* __restrict__ ginP)
{
    __shared__ __align__(16) float lds_g[8][8][16][20];

    const int tid = threadIdx.x;
    const int l = tid & 63;
    const int w = tid >> 6;             // wave 0..7 = K-chunk id
    const int g  = blockIdx.x >> 5;     // batch group (16 batches)
    const int bl = blockIdx.x & 31;     // unit block (32 units)

    short8 barr[8][4];
    {
        const short* wb = wpk + (size_t)(bl * 8 + w) * 16384 + l * 8;
        #pragma unroll
        for (int tl = 0; tl < 8; ++tl)
            #pragma unroll
            for (int s = 0; s < 4; ++s)
                barr[tl][s] = *(const short8*)(wb + tl * 2048 + s * 512);
    }

    const int b16 = tid & 15;
    const int uu  = tid >> 4;
    const int U_  = bl * 32 + uu;
    float c = 0.f;

    const size_t hoff = (size_t)g * 16384 + bl * 512
                        + ((uu >> 3) * 16 + b16) * 8 + (uu & 7);

    float gv[4];
    {
        const short* gb = ginP + (((size_t)g * 64 + (U_ >> 4)) * 4) * 256
                          + (U_ & 15) * 16 + b16;
        #pragma unroll
        for (int q = 0; q < 4; ++q) gv[q] = bf2f(gb[q * 256]);
    }

    for (int t = 0; t < PP; ++t) {
        if (t > 0) {
            const unsigned* A = hst + (size_t)(t - 1) * HSTEP32 + g * 16384
                                + (w * 4) * 512 + l * 8;
            int4v d[8];
            unsigned stale = 0xFu;
            do {
                #pragma unroll
                for (int s = 0; s < 4; ++s)
                    if (stale & (1u << s)) {
                        asm volatile("global_load_dwordx4 %0, %1, off sc0 sc1"
                                     : "=v"(d[2 * s]) : "v"(A + s * 512) : "memory");
                        asm volatile("global_load_dwordx4 %0, %1, off sc0 sc1"
                                     : "=v"(d[2 * s + 1]) : "v"(A + s * 512 + 4) : "memory");
                    }
                asm volatile("s_waitcnt vmcnt(0)" ::: "memory");
                __builtin_amdgcn_sched_barrier(0);
                #pragma unroll
                for (int s = 0; s < 4; ++s)
                    if (stale & (1u << s)) {
                        int ok = 1;
                        #pragma unroll
                        for (int i = 0; i < 2; ++i)
                            #pragma unroll
                            for (int j = 0; j < 4; ++j)
                                ok &= ((((unsigned)d[2 * s + i][j]) & 0xFFFFu)
                                       == (unsigned)t);
                        if (__all(ok)) stale &= ~(1u << s);
                    }
                if (stale) __builtin_amdgcn_s_sleep(1);
            } while (stale);

            floatx4 acc[8];
            #pragma unroll
            for (int tl = 0; tl < 8; ++tl) acc[tl] = (floatx4)0.f;
            #pragma unroll
            for (int s = 0; s < 4; ++s) {
                int4v pk;
                pk[0] = (int)((((unsigned)d[2*s][0]) >> 16)   | (((unsigned)d[2*s][1])   & 0xFFFF0000u));
                pk[1] = (int)((((unsigned)d[2*s][2]) >> 16)   | (((unsigned)d[2*s][3])   & 0xFFFF0000u));
                pk[2] = (int)((((unsigned)d[2*s+1][0]) >> 16) | (((unsigned)d[2*s+1][1]) & 0xFFFF0000u));
                pk[3] = (int)((((unsigned)d[2*s+1][2]) >> 16) | (((unsigned)d[2*s+1][3]) & 0xFFFF0000u));
                short8 av = __builtin_bit_cast(short8, pk);
                #pragma unroll
                for (int tl = 0; tl < 8; ++tl)
                    acc[tl] = __builtin_amdgcn_mfma_f32_16x16x32_bf16(
                        av, barr[tl][s], acc[tl], 0, 0, 0);
            }
            #pragma unroll
            for (int tl = 0; tl < 8; ++tl)
                *(floatx4*)&lds_g[w][tl][l & 15][(l >> 4) * 4] = acc[tl];
            lds_barrier();   // publish LDS; vmcnt (h-store ack) stays in flight
        }

        {
            float s0 = gv[0], s1 = gv[1], s2 = gv[2], s3 = gv[3];
            if (t > 0) {
                #pragma unroll
                for (int w2 = 0; w2 < 8; ++w2) {
                    s0 += lds_g[w2][0 + (uu >> 4)][uu & 15][b16];
                    s1 += lds_g[w2][2 + (uu >> 4)][uu & 15][b16];
                    s2 += lds_g[w2][4 + (uu >> 4)][uu & 15][b16];
                    s3 += lds_g[w2][6 + (uu >> 4)][uu & 15][b16];
                }
            }
            float i_ = sigf(s0), f_ = sigf(s1), g_ = tanhfast(s2), o_ = sigf(s3);
            c = f_ * c + i_ * g_;
            unsigned hd = (((unsigned)(unsigned short)f2bf(o_ * tanhfast(c))) << 16)
                          | (unsigned)(t + 1);
            unsigned* hp = hst + (size_t)t * HSTEP32 + hoff;
            asm volatile("global_store_dword %0, %1, off sc0 sc1"
                         :: "v"(hp), "v"(hd) : "memory");

            if (t + 1 < PP) {
                const short* gb = ginP + ((((size_t)(t + 1) * GRP + g) * 64
                                          + (U_ >> 4)) * 4) * 256 + (U_ & 15) * 16 + b16;
                #pragma unroll
                for (int q = 0; q < 4; ++q) gv[q] = bf2f(gb[q * 256]);
            }
        }
        lds_barrier();   // protect lds_g reuse next step; no vmcnt drain
    }
}

// -------- tag head + log_softmax fused: one block per batch b ---------------
__global__ __launch_bounds__(256) void tagsm_kernel(
    const unsigned* __restrict__ hst, const short* __restrict__ outw_bf,
    const float* __restrict__ out_b, float* __restrict__ out)
{
    __shared__ float sm[PP][52];
    __shared__ float lzb[64];
    const int tid = threadIdx.x;
    const int l = tid & 63, wv = tid >> 6;
    const int b = blockIdx.x;
    const int lr = l & 15, lh = l >> 4;

    const short* Bw = outw_bf + (size_t)(wv * 16 + lr) * HH + lh * 8;

    floatx4 acc[5];
    #pragma unroll
    for (int m = 0; m < 5; ++m) acc[m] = (floatx4)0.f;

    for (int kk = 0; kk < 32; ++kk) {
        short8 bfr = *(const short8*)(Bw + kk * 32);
        #pragma unroll
        for (int m = 0; m < 5; ++m) {
            int q = b * PP + m * 16 + lr;        // flat row (t,b2) = q
            int t = q >> 6, gg = (q >> 4) & 3, b16 = q & 15;
            const unsigned* ap = hst + (size_t)t * HSTEP32 + gg * 16384
                                 + kk * 512 + (lh * 16 + b16) * 8;
            int4v d0 = *(const int4v*)(ap);
            int4v d1 = *(const int4v*)(ap + 4);
            int4v pk;
            pk[0] = (int)((((unsigned)d0[0]) >> 16) | (((unsigned)d0[1]) & 0xFFFF0000u));
            pk[1] = (int)((((unsigned)d0[2]) >> 16) | (((unsigned)d0[3]) & 0xFFFF0000u));
            pk[2] = (int)((((unsigned)d1[0]) >> 16) | (((unsigned)d1[1]) & 0xFFFF0000u));
            pk[3] = (int)((((unsigned)d1[2]) >> 16) | (((unsigned)d1[3]) & 0xFFFF0000u));
            short8 a = __builtin_bit_cast(short8, pk);
            acc[m] = __builtin_amdgcn_mfma_f32_16x16x32_bf16(a, bfr, acc[m], 0, 0, 0);
        }
    }
    int col = wv * 16 + lr;
    if (col < TAGS) {
        float bias = out_b[col];
        #pragma unroll
        for (int m = 0; m < 5; ++m)
            #pragma unroll
            for (int q4 = 0; q4 < 4; ++q4)
                sm[m * 16 + lh * 4 + q4][col] = acc[m][q4] + bias;
    }
    __syncthreads();

    if (tid < TAGS) {
        float mx = -1e30f;
        for (int p = 0; p < PP; ++p) mx = fmaxf(mx, sm[p][tid]);
        float s = 0.f;
        for (int p = 0; p < PP; ++p) s += __expf(sm[p][tid] - mx);
        lzb[tid] = mx + __logf(s);
    }
    __syncthreads();

    for (int idx = tid; idx < PP * TAGS; idx += 256) {
        int p = idx / TAGS, j = idx - p * TAGS;
        out[(size_t)b * (PP * TAGS) + idx] = sm[p][j] - lzb[j];
    }
}

extern "C" void kernel_launch(void* const* d_in, const int* in_sizes, int n_in,
                              void* d_out, int out_size, void* d_ws, size_t ws_size,
                              hipStream_t stream)
{
    const int*   sent     = (const int*)d_in[0];
    const int*   chars    = (const int*)d_in[1];
    const float* word_emb = (const float*)d_in[2];
    const float* char_emb = (const float*)d_in[3];
    const float* conv_w   = (const float*)d_in[4];
    const float* conv_b   = (const float*)d_in[5];
    const float* w_ih     = (const float*)d_in[6];
    const float* w_hh     = (const float*)d_in[7];
    const float* b_ih     = (const float*)d_in[8];
    const float* b_hh     = (const float*)d_in[9];
    const float* out_w    = (const float*)d_in[10];
    const float* out_b    = (const float*)d_in[11];
    float* out = (float*)d_out;

    short* X_bf     = (short*)d_ws;                            // 5120*288
    short* wih_bf   = X_bf + (size_t)ROWS * KPAD;              // 4096*288
    short* wpk      = wih_bf + (size_t)NG * KPAD;              // 4096*1024 (frag-major)
    short* outw_bf  = wpk + (size_t)NG * HH;                   // 64*1024
    short* ginP     = outw_bf + (size_t)64 * HH;               // 4096*5120
    unsigned* hst32 = (unsigned*)(ginP + (size_t)NG * ROWS);   // 80*HSTEP32 dwords

    hipLaunchKernelGGL(prep_embed_kernel, dim3(PREPB + ROWS), dim3(256), 0, stream,
                       w_ih, w_hh, out_w, wih_bf, wpk, outw_bf, hst32,
                       sent, chars, word_emb, char_emb, conv_w, conv_b, X_bf);
    hipLaunchKernelGGL(gemm_in_kernel, dim3(PP, NG / 128), dim3(256), 0, stream,
                       X_bf, wih_bf, b_ih, b_hh, ginP);
    hipLaunchKernelGGL(lstm_seq_kernel, dim3(NBLK), dim3(512), 0, stream,
                       hst32, wpk, ginP);
    hipLaunchKernelGGL(tagsm_kernel, dim3(BB), dim3(256), 0, stream,
                       hst32, outw_bf, out_b, out);
}